// Round 4
// baseline (411.412 us; speedup 1.0000x reference)
//
#include <hip/hip_runtime.h>

// VQ-VAE quantizer, MI355X — fp32 I/O. 4 launches:
//   prep    : blocks 0..255  -> codebook to bf16 MFMA-B-fragment layout + fp32 wnorm
//             blocks 256..383-> M2T[o][e] = <w_e, conv_w_o> + conv_b[o] in exact fp32
//   argmin32: BARRIER-FREE distance GEMM. 1 wave/block, 32 pos x 256 codes, grid 2048
//             (8 independent waves/CU). Single-wave LDS staging is in-order -> no
//             __syncthreads anywhere; waves free-run so z-loads/MFMA/L2-loads overlap
//             across the 8 resident waves instead of phase-locking (round-1/3 profile:
//             everything idle at any occupancy -> barrier convoy was the suspect).
//   out_k   : round-0 proven writer: 8192 blocks, one (b,o) plane each, 32 blocks/CU
//             of pure gather+stream-write; block 0 fuses loss+perplexity epilogue.

#define C_DIM 512
#define N_E   256
#define HW    4096
#define SAr2  40    // argmin32 A_lds row stride in u16 (32 + 8 pad): 2-way-free banks

typedef unsigned short u16;
typedef u16   u16x4 __attribute__((ext_vector_type(4)));
typedef u16   u16x8 __attribute__((ext_vector_type(8)));
typedef short s16x8 __attribute__((ext_vector_type(8)));   // bf16 MFMA fragment (4 VGPRs)
typedef float f32x4 __attribute__((ext_vector_type(4)));

__device__ __forceinline__ u16 f2bf(float f) {
    unsigned u = __float_as_uint(f);
    return (u16)((u + 0x7FFFu + ((u >> 16) & 1u)) >> 16);   // RNE
}

// ---------------- prep: wfrag/wnorm (blocks <256) + fp32 M2T (blocks >=256) --
// wfrag element (code c, k): ntg=c>>4, lane=(c&15)|(((k>>3)&3)<<4), ksg=k>>5, j=k&7
__global__ __launch_bounds__(256)
void prep(const float* __restrict__ emb, const float* __restrict__ stdp,
          const float* __restrict__ means, const float* __restrict__ convw,
          const float* __restrict__ convb,
          u16* __restrict__ wfrag, float* __restrict__ wnorm,
          float* __restrict__ M2T, float* __restrict__ accum,
          unsigned int* __restrict__ hist) {
    int t = threadIdx.x;
    float stdv  = fabsf(stdp[0]);
    float meanv = (means[0] + means[1] + means[2]) * (1.0f / 3.0f);

    if (blockIdx.x < 256) {
        int c = blockIdx.x;          // code
        if (c == 0) {                // zero reduction scratch (re-poisoned each call)
            hist[t] = 0u;
            if (t < 2) accum[t] = 0.f;
        }
        float ss = 0.f;
        for (int k = t; k < C_DIM; k += 256) {
            float w = emb[c * C_DIM + k] * stdv + meanv;
            ss += w * w;                               // fp32 norm (matches np ref)
            int ntg  = c >> 4;
            int lane = (c & 15) | (((k >> 3) & 3) << 4);
            int ksg  = k >> 5;
            int j    = k & 7;
            wfrag[((ntg * 16 + ksg) * 64 + lane) * 8 + j] = f2bf(w);
        }
        #pragma unroll
        for (int m = 1; m < 64; m <<= 1) ss += __shfl_xor(ss, m, 64);
        __shared__ float red[4];
        if ((t & 63) == 0) red[t >> 6] = ss;
        __syncthreads();
        if (t == 0) wnorm[c] = red[0] + red[1] + red[2] + red[3];
    } else {
        // M2T block: 4 o-rows x 256 e, exact fp32. convw rows staged in LDS
        // (broadcast reads), each thread streams its emb row (L2-hot, 512KB table).
        __shared__ float cw[4][C_DIM];                 // 8 KB
        int o0 = (blockIdx.x - 256) * 4;
        for (int i = t; i < 4 * C_DIM; i += 256)
            cw[i >> 9][i & 511] = convw[(o0 + (i >> 9)) * C_DIM + (i & 511)];
        __syncthreads();
        float a0 = 0.f, a1 = 0.f, a2 = 0.f, a3 = 0.f;
        const float* er = emb + t * C_DIM;             // e = t
        #pragma unroll 4
        for (int k = 0; k < C_DIM; k += 4) {
            f32x4 ev = *(const f32x4*)(er + k);
            #pragma unroll
            for (int jj = 0; jj < 4; ++jj) {
                float w = ev[jj] * stdv + meanv;
                a0 += cw[0][k + jj] * w;
                a1 += cw[1][k + jj] * w;
                a2 += cw[2][k + jj] * w;
                a3 += cw[3][k + jj] * w;
            }
        }
        M2T[(o0 + 0) * N_E + t] = a0 + convb[o0 + 0];
        M2T[(o0 + 1) * N_E + t] = a1 + convb[o0 + 1];
        M2T[(o0 + 2) * N_E + t] = a2 + convb[o0 + 2];
        M2T[(o0 + 3) * N_E + t] = a3 + convb[o0 + 3];
    }
}

// ---------------- argmin32: 1-wave barrier-free distance GEMM ----------------
// Block = 1 wave = 32 pos x 256 codes. Grid 2048 (16 b x 128 pos-tiles).
// Per ksg (32 ch): stage 32x32 z-chunk to LDS (transpose), read 2 A-frags,
// stream 16 B-frags from L2-hot wfrag, 32 MFMA. acc[2][16] f32x4.
// No __syncthreads: single-wave DS ops are in-order.
__global__ __launch_bounds__(64, 2)
void argmin32(const float* __restrict__ z, const u16* __restrict__ wfrag,
              const float* __restrict__ wnorm, u16* __restrict__ idxs,
              float* __restrict__ accum, unsigned int* __restrict__ hist) {
    __shared__ u16 As[2][32 * SAr2];           // 2 x 2.5 KB
    __shared__ u16 lcode[32];
    __shared__ unsigned int lhist[N_E];

    int t = threadIdx.x;                       // 64 threads = 1 wave
    int pg = t & 7, cg = t >> 3;               // staging: 4-pos group x 4-ch group
    int m15 = t & 15, quad = t >> 4;
    int bb = blockIdx.x;                       // b = bb>>7, p0 = (bb&127)*32
    const float* zb = z + (size_t)(bb >> 7) * (C_DIM * HW) + (bb & 127) * 32;

    for (int i = t; i < N_E; i += 64) lhist[i] = 0u;

    f32x4 acc[2][16];
    #pragma unroll
    for (int mt = 0; mt < 2; ++mt)
        #pragma unroll
        for (int nt = 0; nt < 16; ++nt)
            acc[mt][nt] = (f32x4){0.f, 0.f, 0.f, 0.f};

    const u16x8* wf8 = (const u16x8*)wfrag;
    float zs = 0.f;

    f32x4 sv[2][4];
    #pragma unroll
    for (int i = 0; i < 4; ++i)
        sv[0][i] = *(const f32x4*)(zb + (size_t)(cg * 4 + i) * HW + pg * 4);

    #pragma unroll
    for (int ksg = 0; ksg < 16; ++ksg) {
        int cb = ksg & 1;
        // pack + LDS store (needs sv[cb] landed; compiler inserts vmcnt)
        #pragma unroll
        for (int p = 0; p < 4; ++p) {
            u16x4 pk;
            #pragma unroll
            for (int i = 0; i < 4; ++i) { float f = sv[cb][i][p]; zs += f * f; pk[i] = f2bf(f); }
            *(u16x4*)(&As[cb][(pg * 4 + p) * SAr2 + cg * 4]) = pk;
        }
        // prefetch next ksg's z-chunk (flies during this ksg's MFMA section)
        if (ksg < 15) {
            #pragma unroll
            for (int i = 0; i < 4; ++i)
                sv[cb ^ 1][i] = *(const f32x4*)(zb + (size_t)((ksg + 1) * 32 + cg * 4 + i) * HW + pg * 4);
        }
        // A-frags: one ds_read_b128 per mt (in-order DS after the writes above)
        s16x8 am[2];
        #pragma unroll
        for (int mt = 0; mt < 2; ++mt)
            am[mt] = __builtin_bit_cast(s16x8,
                *(const u16x8*)(&As[cb][(mt * 16 + m15) * SAr2 + quad * 8]));
        // 16 B-frags (L2-hot), 2 MFMA each
        #pragma unroll
        for (int nt = 0; nt < 16; ++nt) {
            s16x8 bfr = __builtin_bit_cast(s16x8, wf8[(nt * 16 + ksg) * 64 + t]);
            acc[0][nt] = __builtin_amdgcn_mfma_f32_16x16x32_bf16(am[0], bfr, acc[0][nt], 0, 0, 0);
            acc[1][nt] = __builtin_amdgcn_mfma_f32_16x16x32_bf16(am[1], bfr, acc[1][nt], 0, 0, 0);
        }
    }

    // ---- scoring: d = wnorm - 2*dot; wave owns all 256 codes -> no atomicMin.
    float wn[16];
    #pragma unroll
    for (int nt = 0; nt < 16; ++nt) wn[nt] = wnorm[nt * 16 + m15];

    float dsum = 0.f;
    #pragma unroll
    for (int mt = 0; mt < 2; ++mt) {
        #pragma unroll
        for (int r = 0; r < 4; ++r) {
            unsigned long long key = ~0ull;
            #pragma unroll
            for (int nt = 0; nt < 16; ++nt) {
                float d = wn[nt] - 2.0f * acc[mt][nt][r];
                unsigned u = __float_as_uint(d);
                u ^= (u >> 31) ? 0xFFFFFFFFu : 0x80000000u;   // monotone float->uint
                unsigned long long k2 = ((unsigned long long)u << 32)
                                      | (unsigned)(nt * 16 + m15);
                key = (k2 < key) ? k2 : key;
            }
            #pragma unroll
            for (int sm = 1; sm < 16; sm <<= 1) {             // reduce across m15
                unsigned long long o2 = (unsigned long long)__shfl_xor((long long)key, sm, 64);
                key = (o2 < key) ? o2 : key;
            }
            if (m15 == 0) {                                   // lanes 0,16,32,48
                int pos = mt * 16 + quad * 4 + r;             // all 32 pos covered once
                unsigned code = (unsigned)(key & 0xFFFFu);
                unsigned u = (unsigned)(key >> 32);
                u ^= (u >> 31) ? 0x80000000u : 0xFFFFFFFFu;   // inverse transform
                dsum += __uint_as_float(u);
                lcode[pos] = (u16)code;
                atomicAdd(&lhist[code], 1u);
            }
        }
    }
    #pragma unroll
    for (int sm = 1; sm < 64; sm <<= 1) {
        zs   += __shfl_xor(zs, sm, 64);
        dsum += __shfl_xor(dsum, sm, 64);
    }
    if (t == 0) {
        atomicAdd(&accum[0], zs);      // Sum z^2
        atomicAdd(&accum[1], dsum);    // Sum d_min
    }
    // idxs + hist flush (single wave: DS in-order, no barrier needed)
    if (t < 32) idxs[(bb >> 7) * HW + (bb & 127) * 32 + t] = lcode[t];
    for (int i = t; i < N_E; i += 64) {
        unsigned cnt = lhist[i];
        if (cnt) atomicAdd(&hist[i], cnt);
    }
}

// ---------------- out_k: out[b,o,:] = M2T[o][idx[b,:]]; block0 adds scalars --
__global__ __launch_bounds__(256)
void out_k(const float* __restrict__ M2T, const u16* __restrict__ idxs,
           float* __restrict__ out, const float* __restrict__ accum,
           const unsigned int* __restrict__ hist) {
    __shared__ float col[N_E];
    int tid = threadIdx.x;
    int bk = blockIdx.x;                 // [b:16][o:512] -> one (b,o) plane per block
    int o = bk & 511, b = bk >> 9;
    col[tid] = M2T[o * N_E + tid];
    __syncthreads();
    size_t obase = (size_t)b * (C_DIM * HW) + (size_t)o * HW;
    #pragma unroll
    for (int j = 0; j < 4; ++j) {
        int p4 = (j * 256 + tid) * 4;
        u16x4 ids = *(const u16x4*)(idxs + b * HW + p4);
        f32x4 r;
        #pragma unroll
        for (int jj = 0; jj < 4; ++jj) r[jj] = col[ids[jj]];
        *(f32x4*)(out + obase + p4) = r;
    }
    if (bk == 0) {                       // fused scalar epilogue (loss + perplexity)
        float e = (float)hist[tid] * (1.0f / 65536.0f);
        float term = e * logf(e + 1e-10f);
        #pragma unroll
        for (int m = 1; m < 64; m <<= 1) term += __shfl_xor(term, m, 64);
        __shared__ float red[4];
        if ((tid & 63) == 0) red[tid >> 6] = term;
        __syncthreads();
        if (tid == 0) {
            float s = red[0] + red[1] + red[2] + red[3];
            out[33554432] = 1.25f * (accum[0] + accum[1]) * (1.0f / 33554432.0f);
            out[33554433] = expf(-s);
        }
    }
}

extern "C" void kernel_launch(void* const* d_in, const int* in_sizes, int n_in,
                              void* d_out, int out_size, void* d_ws, size_t ws_size,
                              hipStream_t stream) {
    (void)in_sizes; (void)n_in; (void)out_size; (void)ws_size;
    const float* z     = (const float*)d_in[0];   // [16][512][64][64] fp32
    const float* emb   = (const float*)d_in[1];   // [256][512] fp32
    const float* stdp  = (const float*)d_in[2];   // scalar
    const float* means = (const float*)d_in[3];   // [3]
    const float* convw = (const float*)d_in[4];   // [512][512] fp32
    const float* convb = (const float*)d_in[5];   // [512]

    char* ws = (char*)d_ws;
    u16*   wfrag = (u16*)(ws + 0);            // 262144 B (bf16 B-fragments)
    float* wnorm = (float*)(ws + 262144);     // 1024 B
    float* M2T   = (float*)(ws + 263168);     // 524288 B  [o][e] fp32
    u16*   idxs  = (u16*)(ws + 787456);       // 131072 B
    float* accum = (float*)(ws + 918528);     // 8 B  [zsq, dsum]
    unsigned int* hist = (unsigned int*)(ws + 918536);  // 1024 B
    float* out = (float*)d_out;

    prep    <<<384,  256, 0, stream>>>(emb, stdp, means, convw, convb,
                                       wfrag, wnorm, M2T, accum, hist);
    argmin32<<<2048,  64, 0, stream>>>(z, wfrag, wnorm, idxs, accum, hist);
    out_k   <<<8192, 256, 0, stream>>>(M2T, idxs, out, accum, hist);
}